// Round 1
// baseline (576.842 us; speedup 1.0000x reference)
//
#include <hip/hip_runtime.h>

#define C_OBJ 151
#define N_OBJ 512
#define N_RELK 16384
#define C_REL 51
#define DDIM 4096

#define OUT_PREDS 77312
#define OUT_REL   77824

typedef float f32x4 __attribute__((ext_vector_type(4)));
typedef __bf16 bf16x8 __attribute__((ext_vector_type(8)));

__device__ inline unsigned short f2bf_rne(float x) {
  unsigned int u = __float_as_uint(x);
  unsigned int r = (u + 0x7FFFu + ((u >> 16) & 1u)) >> 16;
  return (unsigned short)r;
}
__device__ inline float bf2f(unsigned short h) {
  return __uint_as_float(((unsigned int)h) << 16);
}

// ---------------- softmax + logits copy ----------------
// one wave per object row; probs -> ws
__global__ void softmax_copy_kernel(const float* __restrict__ logits,
                                    float* __restrict__ out,
                                    float* __restrict__ probs) {
  const int o = blockIdx.x;
  const int lane = threadIdx.x;  // 64
  float v[3];
  float mx = -3.4e38f;
#pragma unroll
  for (int j = 0; j < 3; ++j) {
    int c = lane + j * 64;
    if (c < C_OBJ) {
      float x = logits[o * C_OBJ + c];
      out[o * C_OBJ + c] = x;   // obj_dists2 passthrough
      v[j] = x;
      mx = fmaxf(mx, x);
    } else {
      v[j] = -3.4e38f;
    }
  }
  for (int off = 32; off; off >>= 1) mx = fmaxf(mx, __shfl_xor(mx, off));
  float e[3];
  float s = 0.f;
#pragma unroll
  for (int j = 0; j < 3; ++j) {
    int c = lane + j * 64;
    e[j] = (c < C_OBJ) ? expf(v[j] - mx) : 0.f;
    s += e[j];
  }
  for (int off = 32; off; off >>= 1) s += __shfl_xor(s, off);
#pragma unroll
  for (int j = 0; j < 3; ++j) {
    int c = lane + j * 64;
    if (c < C_OBJ) probs[o * C_OBJ + c] = e[j] / s;
  }
}

// ---------------- per-class NMS ----------------
// grid = 150 blocks (classes 1..150), block = 512 threads
__global__ __launch_bounds__(512) void nms_kernel(const float* __restrict__ probs,
                                                  const float* __restrict__ boxes,
                                                  float* __restrict__ masked) {
  const int c = blockIdx.x + 1;
  const int t = threadIdx.x;

  __shared__ float s[N_OBJ];
  __shared__ int id[N_OBJ];
  __shared__ float bx1[N_OBJ], by1[N_OBJ], bx2[N_OBJ], by2[N_OBJ], ar[N_OBJ];
  __shared__ unsigned long long m[N_OBJ][8];
  __shared__ unsigned char keepS[N_OBJ];

  s[t] = probs[t * C_OBJ + c];
  id[t] = t;
  __syncthreads();

  // bitonic sort: total order "before" = (score desc, idx asc)  == stable argsort(-scores)
  for (int k = 2; k <= N_OBJ; k <<= 1) {
    for (int j = k >> 1; j > 0; j >>= 1) {
      int ixj = t ^ j;
      if (ixj > t) {
        float sa = s[t], sb = s[ixj];
        int ia = id[t], ib = id[ixj];
        bool before = (sa > sb) || (sa == sb && ia < ib);
        bool up = ((t & k) == 0);
        if (up ? !before : before) {
          s[t] = sb; s[ixj] = sa;
          id[t] = ib; id[ixj] = ia;
        }
      }
      __syncthreads();
    }
  }

  {
    int o = id[t];
    const float* bp = boxes + ((size_t)o * C_OBJ + c) * 4;
    float X1 = bp[0], Y1 = bp[1], X2 = bp[2], Y2 = bp[3];
    bx1[t] = X1; by1[t] = Y1; bx2[t] = X2; by2[t] = Y2;
    ar[t] = (X2 - X1 + 1.f) * (Y2 - Y1 + 1.f);
  }
  __syncthreads();

  // suppression bitmask matrix: bit j of m[i][w] = IoU(i, w*64+j) > 0.3
  {
    float X1 = bx1[t], Y1 = by1[t], X2 = bx2[t], Y2 = by2[t], A = ar[t];
    for (int w = 0; w < 8; ++w) {
      unsigned long long bits = 0ull;
      for (int jj = 0; jj < 64; ++jj) {
        int j = (w << 6) + jj;
        float xx1 = fmaxf(X1, bx1[j]);
        float yy1 = fmaxf(Y1, by1[j]);
        float xx2 = fminf(X2, bx2[j]);
        float yy2 = fminf(Y2, by2[j]);
        float ww = fmaxf(xx2 - xx1 + 1.f, 0.f);
        float hh = fmaxf(yy2 - yy1 + 1.f, 0.f);
        float inter = ww * hh;
        float iou = inter / (A + ar[j] - inter);
        if (iou > 0.3f) bits |= (1ull << jj);
      }
      m[t][w] = bits;
    }
  }
  __syncthreads();

  // greedy scan, wave-cooperative (first wave; sup words live in registers, 8 replicas)
  if (t < 64) {
    const int w = t & 7;
    unsigned long long supw = 0ull;
    for (int i = 0; i < N_OBJ; ++i) {
      unsigned long long srcw = __shfl(supw, i >> 6);
      int kept = !((srcw >> (i & 63)) & 1ull);
      if (t == 0) keepS[i] = (unsigned char)kept;
      unsigned long long row = m[i][w];
      if (kept) supw |= row;
    }
  }
  __syncthreads();

  masked[(size_t)id[t] * (C_OBJ - 1) + (c - 1)] =
      keepS[t] ? probs[(size_t)id[t] * C_OBJ + c] : 0.f;
}

// ---------------- argmax over masked probs ----------------
// one wave per object; first-max-index (ties -> smallest class) matches jnp.argmax
__global__ void argmax_kernel(const float* __restrict__ masked,
                              float* __restrict__ outp) {
  const int o = blockIdx.x * 4 + (threadIdx.x >> 6);
  const int lane = threadIdx.x & 63;
  float bv = -1.f;
  int bc = 1 << 20;
  for (int j = lane; j < C_OBJ - 1; j += 64) {
    float x = masked[(size_t)o * (C_OBJ - 1) + j];
    int cc = j + 1;
    if (x > bv || (x == bv && cc < bc)) { bv = x; bc = cc; }
  }
  for (int off = 32; off; off >>= 1) {
    float ov = __shfl_xor(bv, off);
    int oc = __shfl_xor(bc, off);
    if (ov > bv || (ov == bv && oc < bc)) { bv = ov; bc = oc; }
  }
  if (lane == 0) outp[o] = (float)bc;
}

// ---------------- bf16-split MFMA GEMM: rel = vr @ W^T + b ----------------
// grid 256 blocks x 256 threads; M_TILE=64 rows, N=64 (51 padded), K_STEP=32
#define LDS_STRIDE 40  // ushorts per row: 32 + 8 pad -> 2-way-max bank aliasing (free)
__global__ __launch_bounds__(256) void gemm_kernel(const float* __restrict__ A,
                                                   const float* __restrict__ W,
                                                   const float* __restrict__ bias,
                                                   float* __restrict__ out) {
  __shared__ unsigned short aHi[64 * LDS_STRIDE], aLo[64 * LDS_STRIDE];
  __shared__ unsigned short bHi[64 * LDS_STRIDE], bLo[64 * LDS_STRIDE];

  const int t = threadIdx.x;
  const int bm = blockIdx.x * 64;
  const int wave = t >> 6;
  const int lane = t & 63;

  const int sr0 = t >> 3;        // 0..31
  const int sr1 = 32 + sr0;      // 32..63
  const int sc = (t & 7) * 4;    // 0..28

  float4 pa0, pa1, pb0, pb1;
  const float4 z4 = make_float4(0.f, 0.f, 0.f, 0.f);

  auto loadT = [&](int kt) {
    const int ko = kt * 32 + sc;
    pa0 = *(const float4*)(A + (size_t)(bm + sr0) * DDIM + ko);
    pa1 = *(const float4*)(A + (size_t)(bm + sr1) * DDIM + ko);
    pb0 = *(const float4*)(W + (size_t)sr0 * DDIM + ko);  // sr0 < 32 < 51 always valid
    pb1 = (sr1 < C_REL) ? *(const float4*)(W + (size_t)sr1 * DDIM + ko) : z4;
  };

  auto cw = [&](float4 v, unsigned short* hp, unsigned short* lp) {
    ushort4 h, l;
    float x;
    x = v.x; h.x = f2bf_rne(x); l.x = f2bf_rne(x - bf2f(h.x));
    x = v.y; h.y = f2bf_rne(x); l.y = f2bf_rne(x - bf2f(h.y));
    x = v.z; h.z = f2bf_rne(x); l.z = f2bf_rne(x - bf2f(h.z));
    x = v.w; h.w = f2bf_rne(x); l.w = f2bf_rne(x - bf2f(h.w));
    *(ushort4*)hp = h;
    *(ushort4*)lp = l;
  };

  f32x4 acc0 = {0.f, 0.f, 0.f, 0.f};
  f32x4 acc1 = acc0, acc2 = acc0, acc3 = acc0;

  const int aoff = (wave * 16 + (lane & 15)) * LDS_STRIDE + (lane >> 4) * 8;
  const int boff = (lane & 15) * LDS_STRIDE + (lane >> 4) * 8;

  loadT(0);
  for (int kt = 0; kt < DDIM / 32; ++kt) {
    __syncthreads();  // previous iteration's LDS reads complete
    cw(pa0, aHi + sr0 * LDS_STRIDE + sc, aLo + sr0 * LDS_STRIDE + sc);
    cw(pa1, aHi + sr1 * LDS_STRIDE + sc, aLo + sr1 * LDS_STRIDE + sc);
    cw(pb0, bHi + sr0 * LDS_STRIDE + sc, bLo + sr0 * LDS_STRIDE + sc);
    cw(pb1, bHi + sr1 * LDS_STRIDE + sc, bLo + sr1 * LDS_STRIDE + sc);
    __syncthreads();
    if (kt + 1 < DDIM / 32) loadT(kt + 1);  // prefetch overlaps MFMA phase

    bf16x8 ah = *(const bf16x8*)(aHi + aoff);
    bf16x8 al = *(const bf16x8*)(aLo + aoff);
#define NTILE(ACC, N)                                                          \
    {                                                                          \
      bf16x8 bh = *(const bf16x8*)(bHi + boff + (N) * 16 * LDS_STRIDE);        \
      bf16x8 bl = *(const bf16x8*)(bLo + boff + (N) * 16 * LDS_STRIDE);        \
      ACC = __builtin_amdgcn_mfma_f32_16x16x32_bf16(ah, bh, ACC, 0, 0, 0);     \
      ACC = __builtin_amdgcn_mfma_f32_16x16x32_bf16(al, bh, ACC, 0, 0, 0);     \
      ACC = __builtin_amdgcn_mfma_f32_16x16x32_bf16(ah, bl, ACC, 0, 0, 0);     \
    }
    NTILE(acc0, 0)
    NTILE(acc1, 1)
    NTILE(acc2, 2)
    NTILE(acc3, 3)
#undef NTILE
  }

  // epilogue: C/D layout col = lane&15, row = (lane>>4)*4 + reg
  const int r0 = bm + wave * 16 + (lane >> 4) * 4;
#define EPI(ACC, N)                                                            \
  {                                                                            \
    int cc = (N) * 16 + (lane & 15);                                           \
    if (cc < C_REL) {                                                          \
      float bv = bias[cc];                                                     \
      out[(size_t)(r0 + 0) * C_REL + cc] = ACC[0] + bv;                        \
      out[(size_t)(r0 + 1) * C_REL + cc] = ACC[1] + bv;                        \
      out[(size_t)(r0 + 2) * C_REL + cc] = ACC[2] + bv;                        \
      out[(size_t)(r0 + 3) * C_REL + cc] = ACC[3] + bv;                        \
    }                                                                          \
  }
  EPI(acc0, 0)
  EPI(acc1, 1)
  EPI(acc2, 2)
  EPI(acc3, 3)
#undef EPI
}

extern "C" void kernel_launch(void* const* d_in, const int* in_sizes, int n_in,
                              void* d_out, int out_size, void* d_ws, size_t ws_size,
                              hipStream_t stream) {
  const float* logits = (const float*)d_in[0];
  const float* vr     = (const float*)d_in[1];
  const float* boxes  = (const float*)d_in[2];
  const float* W      = (const float*)d_in[3];
  const float* bias   = (const float*)d_in[4];
  float* out = (float*)d_out;
  float* ws  = (float*)d_ws;

  float* probs  = ws;                         // 512*151 f32
  float* masked = ws + N_OBJ * C_OBJ;         // 512*150 f32

  hipLaunchKernelGGL(softmax_copy_kernel, dim3(N_OBJ), dim3(64), 0, stream,
                     logits, out, probs);
  hipLaunchKernelGGL(nms_kernel, dim3(C_OBJ - 1), dim3(N_OBJ), 0, stream,
                     probs, boxes, masked);
  hipLaunchKernelGGL(argmax_kernel, dim3(N_OBJ / 4), dim3(256), 0, stream,
                     masked, out + OUT_PREDS);
  hipLaunchKernelGGL(gemm_kernel, dim3(N_RELK / 64), dim3(256), 0, stream,
                     vr, W, bias, out + OUT_REL);
}

// Round 3
// 518.186 us; speedup vs baseline: 1.1132x; 1.1132x over previous
//
#include <hip/hip_runtime.h>

#define C_OBJ 151
#define N_OBJ 512
#define N_RELK 16384
#define C_REL 51
#define DDIM 4096
#define KSPLIT 2
#define KHALF (DDIM / KSPLIT)   // 2048
#define KSTEPS (KHALF / 32)     // 64
#define PF 4                    // A prefetch depth (K-steps)

#define OUT_PREDS 77312
#define OUT_REL   77824

typedef float f32x4 __attribute__((ext_vector_type(4)));
typedef __bf16 bf16x8 __attribute__((ext_vector_type(8)));
typedef unsigned short u16x8 __attribute__((ext_vector_type(8)));

__device__ inline unsigned short f2bf_rne(float x) {
  unsigned int u = __float_as_uint(x);
  unsigned int r = (u + 0x7FFFu + ((u >> 16) & 1u)) >> 16;
  return (unsigned short)r;
}
__device__ inline float bf2f(unsigned short h) {
  return __uint_as_float(((unsigned int)h) << 16);
}

// ---------------- softmax + logits copy ----------------
__global__ void softmax_copy_kernel(const float* __restrict__ logits,
                                    float* __restrict__ out,
                                    float* __restrict__ probs) {
  const int o = blockIdx.x;
  const int lane = threadIdx.x;  // 64
  float v[3];
  float mx = -3.4e38f;
#pragma unroll
  for (int j = 0; j < 3; ++j) {
    int c = lane + j * 64;
    if (c < C_OBJ) {
      float x = logits[o * C_OBJ + c];
      out[o * C_OBJ + c] = x;
      v[j] = x;
      mx = fmaxf(mx, x);
    } else {
      v[j] = -3.4e38f;
    }
  }
  for (int off = 32; off; off >>= 1) mx = fmaxf(mx, __shfl_xor(mx, off));
  float e[3];
  float s = 0.f;
#pragma unroll
  for (int j = 0; j < 3; ++j) {
    int c = lane + j * 64;
    e[j] = (c < C_OBJ) ? expf(v[j] - mx) : 0.f;
    s += e[j];
  }
  for (int off = 32; off; off >>= 1) s += __shfl_xor(s, off);
#pragma unroll
  for (int j = 0; j < 3; ++j) {
    int c = lane + j * 64;
    if (c < C_OBJ) probs[o * C_OBJ + c] = e[j] / s;
  }
}

// ---------------- per-class NMS (unchanged — validated in R1) ----------------
__global__ __launch_bounds__(512) void nms_kernel(const float* __restrict__ probs,
                                                  const float* __restrict__ boxes,
                                                  float* __restrict__ masked) {
  const int c = blockIdx.x + 1;
  const int t = threadIdx.x;

  __shared__ float s[N_OBJ];
  __shared__ int id[N_OBJ];
  __shared__ float bx1[N_OBJ], by1[N_OBJ], bx2[N_OBJ], by2[N_OBJ], ar[N_OBJ];
  __shared__ unsigned long long m[N_OBJ][8];
  __shared__ unsigned char keepS[N_OBJ];

  s[t] = probs[t * C_OBJ + c];
  id[t] = t;
  __syncthreads();

  for (int k = 2; k <= N_OBJ; k <<= 1) {
    for (int j = k >> 1; j > 0; j >>= 1) {
      int ixj = t ^ j;
      if (ixj > t) {
        float sa = s[t], sb = s[ixj];
        int ia = id[t], ib = id[ixj];
        bool before = (sa > sb) || (sa == sb && ia < ib);
        bool up = ((t & k) == 0);
        if (up ? !before : before) {
          s[t] = sb; s[ixj] = sa;
          id[t] = ib; id[ixj] = ia;
        }
      }
      __syncthreads();
    }
  }

  {
    int o = id[t];
    const float* bp = boxes + ((size_t)o * C_OBJ + c) * 4;
    float X1 = bp[0], Y1 = bp[1], X2 = bp[2], Y2 = bp[3];
    bx1[t] = X1; by1[t] = Y1; bx2[t] = X2; by2[t] = Y2;
    ar[t] = (X2 - X1 + 1.f) * (Y2 - Y1 + 1.f);
  }
  __syncthreads();

  {
    float X1 = bx1[t], Y1 = by1[t], X2 = bx2[t], Y2 = by2[t], A = ar[t];
    for (int w = 0; w < 8; ++w) {
      unsigned long long bits = 0ull;
      for (int jj = 0; jj < 64; ++jj) {
        int j = (w << 6) + jj;
        float xx1 = fmaxf(X1, bx1[j]);
        float yy1 = fmaxf(Y1, by1[j]);
        float xx2 = fminf(X2, bx2[j]);
        float yy2 = fminf(Y2, by2[j]);
        float ww = fmaxf(xx2 - xx1 + 1.f, 0.f);
        float hh = fmaxf(yy2 - yy1 + 1.f, 0.f);
        float inter = ww * hh;
        float iou = inter / (A + ar[j] - inter);
        if (iou > 0.3f) bits |= (1ull << jj);
      }
      m[t][w] = bits;
    }
  }
  __syncthreads();

  if (t < 64) {
    const int w = t & 7;
    unsigned long long supw = 0ull;
    for (int i = 0; i < N_OBJ; ++i) {
      unsigned long long srcw = __shfl(supw, i >> 6);
      int kept = !((srcw >> (i & 63)) & 1ull);
      if (t == 0) keepS[i] = (unsigned char)kept;
      unsigned long long row = m[i][w];
      if (kept) supw |= row;
    }
  }
  __syncthreads();

  masked[(size_t)id[t] * (C_OBJ - 1) + (c - 1)] =
      keepS[t] ? probs[(size_t)id[t] * C_OBJ + c] : 0.f;
}

// ---------------- argmax over masked probs ----------------
__global__ void argmax_kernel(const float* __restrict__ masked,
                              float* __restrict__ outp) {
  const int o = blockIdx.x * 4 + (threadIdx.x >> 6);
  const int lane = threadIdx.x & 63;
  float bv = -1.f;
  int bc = 1 << 20;
  for (int j = lane; j < C_OBJ - 1; j += 64) {
    float x = masked[(size_t)o * (C_OBJ - 1) + j];
    int cc = j + 1;
    if (x > bv || (x == bv && cc < bc)) { bv = x; bc = cc; }
  }
  for (int off = 32; off; off >>= 1) {
    float ov = __shfl_xor(bv, off);
    int oc = __shfl_xor(bc, off);
    if (ov > bv || (ov == bv && oc < bc)) { bv = ov; bc = oc; }
  }
  if (lane == 0) outp[o] = (float)bc;
}

// ---------------- B pre-conversion: fragment-packed bf16 (hi only) ----------
// layout: [kt(128)][n(4)][lane(64)][8]; value = W[n*16+(lane&15)][kt*32+(lane>>4)*8+j]
__global__ void convB_kernel(const float* __restrict__ W,
                             unsigned short* __restrict__ Bhi) {
  const int tid = blockIdx.x * 256 + threadIdx.x;  // 32768 total
  const int kt = tid >> 8;
  const int rem = tid & 255;
  const int n = rem >> 6;
  const int l = rem & 63;
  const int col = n * 16 + (l & 15);
  const int k = kt * 32 + ((l >> 4) << 3);
  u16x8 vh;
#pragma unroll
  for (int j = 0; j < 8; ++j) {
    float x = (col < C_REL) ? W[(size_t)col * DDIM + k + j] : 0.f;
    vh[j] = f2bf_rne(x);
  }
  *(u16x8*)(Bhi + (size_t)tid * 8) = vh;
}

// ---------------- init rel output with bias ----------------
__global__ void init_rel_kernel(const float* __restrict__ bias,
                                float* __restrict__ outrel) {
  const int idx = blockIdx.x * 256 + threadIdx.x;  // 835584 exactly
  const int c = idx - (idx / C_REL) * C_REL;
  outrel[idx] = bias[c];
}

// ---------------- GEMM: reg-direct, split-K=2, 4-deep prefetch, atomic epi --
__global__ __launch_bounds__(256, 2) void gemm_kernel(const float* __restrict__ A,
                                                      const unsigned short* __restrict__ Bhi,
                                                      float* __restrict__ outrel) {
  const int blk = blockIdx.x;      // 512 blocks
  const int ks = blk & (KSPLIT - 1);
  const int mb = blk >> 1;
  const int wave = threadIdx.x >> 6;
  const int lane = threadIdx.x & 63;

  const int row = mb * 64 + wave * 16 + (lane & 15);
  const float* ap = A + (size_t)row * DDIM + ks * KHALF + ((lane >> 4) << 3);
  const unsigned short* bp = Bhi + (size_t)(ks * KSTEPS) * 2048 + (lane << 3);

  f32x4 acc0 = {0.f, 0.f, 0.f, 0.f};
  f32x4 acc1 = acc0, acc2 = acc0, acc3 = acc0;

  f32x4 abuf[PF][2];
#pragma unroll
  for (int u = 0; u < PF; ++u) {
    abuf[u][0] = *(const f32x4*)(ap + u * 32);
    abuf[u][1] = *(const f32x4*)(ap + u * 32 + 4);
  }
  u16x8 bbuf[2][4];
#pragma unroll
  for (int n = 0; n < 4; ++n) bbuf[0][n] = *(const u16x8*)(bp + n * 512);

  for (int kt = 0; kt < KSTEPS; kt += PF) {
#pragma unroll
    for (int u = 0; u < PF; ++u) {
      const int cur = kt + u;
      // prefetch next-step B (ping-pong, static index after unroll)
      {
        int nb = cur + 1;
        if (nb >= KSTEPS) nb = KSTEPS - 1;
        const unsigned short* bq = bp + (size_t)nb * 2048;
#pragma unroll
        for (int n = 0; n < 4; ++n)
          bbuf[(u + 1) & 1][n] = *(const u16x8*)(bq + n * 512);
      }
      // convert A slot u (hi + residual-lo)
      u16x8 uh, ul;
      {
        f32x4 a0 = abuf[u][0], a1 = abuf[u][1];
#define CVT1(i, X) { float x_ = (X); unsigned short h_ = f2bf_rne(x_); uh[i] = h_; ul[i] = f2bf_rne(x_ - bf2f(h_)); }
        CVT1(0, a0.x) CVT1(1, a0.y) CVT1(2, a0.z) CVT1(3, a0.w)
        CVT1(4, a1.x) CVT1(5, a1.y) CVT1(6, a1.z) CVT1(7, a1.w)
#undef CVT1
      }
      // refill A slot u with step cur+PF
      {
        int na = cur + PF;
        if (na >= KSTEPS) na = KSTEPS - 1;
        abuf[u][0] = *(const f32x4*)(ap + (size_t)na * 32);
        abuf[u][1] = *(const f32x4*)(ap + (size_t)na * 32 + 4);
      }
      bf16x8 ah = __builtin_bit_cast(bf16x8, uh);
      bf16x8 al = __builtin_bit_cast(bf16x8, ul);
#define NT(ACC, N)                                                             \
      {                                                                        \
        bf16x8 bh_ = __builtin_bit_cast(bf16x8, bbuf[u & 1][N]);               \
        ACC = __builtin_amdgcn_mfma_f32_16x16x32_bf16(ah, bh_, ACC, 0, 0, 0);  \
        ACC = __builtin_amdgcn_mfma_f32_16x16x32_bf16(al, bh_, ACC, 0, 0, 0);  \
      }
      NT(acc0, 0)
      NT(acc1, 1)
      NT(acc2, 2)
      NT(acc3, 3)
#undef NT
    }
  }

  const int r0 = mb * 64 + wave * 16 + ((lane >> 4) << 2);
#define EPI(ACC, N)                                                            \
  {                                                                            \
    int cc = (N) * 16 + (lane & 15);                                           \
    if (cc < C_REL) {                                                          \
      atomicAdd(&outrel[(size_t)(r0 + 0) * C_REL + cc], ACC[0]);               \
      atomicAdd(&outrel[(size_t)(r0 + 1) * C_REL + cc], ACC[1]);               \
      atomicAdd(&outrel[(size_t)(r0 + 2) * C_REL + cc], ACC[2]);               \
      atomicAdd(&outrel[(size_t)(r0 + 3) * C_REL + cc], ACC[3]);               \
    }                                                                          \
  }
  EPI(acc0, 0)
  EPI(acc1, 1)
  EPI(acc2, 2)
  EPI(acc3, 3)
#undef EPI
}

extern "C" void kernel_launch(void* const* d_in, const int* in_sizes, int n_in,
                              void* d_out, int out_size, void* d_ws, size_t ws_size,
                              hipStream_t stream) {
  const float* logits = (const float*)d_in[0];
  const float* vr     = (const float*)d_in[1];
  const float* boxes  = (const float*)d_in[2];
  const float* W      = (const float*)d_in[3];
  const float* bias   = (const float*)d_in[4];
  float* out = (float*)d_out;
  float* ws  = (float*)d_ws;

  float* probs  = ws;                                  // 77312 f
  float* masked = ws + N_OBJ * C_OBJ;                  // 76800 f
  unsigned short* Bhi = (unsigned short*)(ws + 154112);  // 262144 u16 = 131072 f

  hipLaunchKernelGGL(convB_kernel, dim3(128), dim3(256), 0, stream, W, Bhi);
  hipLaunchKernelGGL(init_rel_kernel, dim3((N_RELK * C_REL) / 256), dim3(256), 0,
                     stream, bias, out + OUT_REL);
  hipLaunchKernelGGL(softmax_copy_kernel, dim3(N_OBJ), dim3(64), 0, stream,
                     logits, out, probs);
  hipLaunchKernelGGL(nms_kernel, dim3(C_OBJ - 1), dim3(N_OBJ), 0, stream,
                     probs, boxes, masked);
  hipLaunchKernelGGL(argmax_kernel, dim3(N_OBJ / 4), dim3(256), 0, stream,
                     masked, out + OUT_PREDS);
  hipLaunchKernelGGL(gemm_kernel, dim3((N_RELK / 64) * KSPLIT), dim3(256), 0,
                     stream, vr, Bhi, out + OUT_REL);
}